// Round 8
// baseline (2668.091 us; speedup 1.0000x reference)
//
#include <hip/hip_runtime.h>
#include <stdint.h>

// ResRnn persistent kernel. R8: detect-once-then-stream.
//  - Producers signal per-wave 16B-padded flags (plain relaxed sc1 stores after
//    own vmcnt(0) drain; no RMW, no fences).
//  - Consumer wave's producer window = 16 chunks x 4 waves = 64 flags: ONE
//    lane-parallel load + __ballot detects the whole window; then ALL 64
//    A-operand loads issue ungated and stream through the VMEM pipe (one LLC
//    latency instead of 16 latency-serialized gated batches -- R6/R7's per-ks
//    gating was the hidden ~6us/phase term).
//  - Ring depth D=2 (safe under wait-all transitivity), sc1 LLC-direct data
//    reads/writes (R7 proved cached == direct), 2 syncthreads/step.

#define NSTEPS 128
#define NB 128
#define WID 2048
#define SS 1984

#define SFN (128 * 1984)   // floats per Sf slot
#define SBN (128 * 1984)   // shorts per Sb slot
#define HN  (128 * 2048)   // shorts per h slot

typedef __attribute__((ext_vector_type(8))) short short8;
typedef __attribute__((ext_vector_type(4))) short short4v;
typedef __attribute__((ext_vector_type(4))) float f32x4;
typedef unsigned long long u64;

static __device__ __forceinline__ short f2bf(float f) {
  union { float f; unsigned u; } v; v.f = f;
  unsigned r = (v.u + 0x7fffu + ((v.u >> 16) & 1u)) >> 16;  // RNE
  return (short)r;
}
static __device__ __forceinline__ short8 pack8(f32x4 lo, f32x4 hi) {
  short8 r;
  r[0] = f2bf(lo[0]); r[1] = f2bf(lo[1]); r[2] = f2bf(lo[2]); r[3] = f2bf(lo[3]);
  r[4] = f2bf(hi[0]); r[5] = f2bf(hi[1]); r[6] = f2bf(hi[2]); r[7] = f2bf(hi[3]);
  return r;
}
static __device__ __forceinline__ void ast64(void* p, u64 v) {
  __hip_atomic_store((u64*)p, v, __ATOMIC_RELAXED, __HIP_MEMORY_SCOPE_AGENT);
}
static __device__ __forceinline__ void ast32(unsigned* p, unsigned v) {
  __hip_atomic_store(p, v, __ATOMIC_RELAXED, __HIP_MEMORY_SCOPE_AGENT);
}
static __device__ __forceinline__ u64 ald64(const void* p) {
  return __hip_atomic_load((const u64*)p, __ATOMIC_RELAXED, __HIP_MEMORY_SCOPE_AGENT);
}
static __device__ __forceinline__ unsigned ald32(const unsigned* p) {
  return __hip_atomic_load(p, __ATOMIC_RELAXED, __HIP_MEMORY_SCOPE_AGENT);
}
static __device__ __forceinline__ short8 ald_s8(const void* p) {
  union { u64 u[2]; short8 s; } r;
  r.u[0] = ald64((const char*)p); r.u[1] = ald64((const char*)p + 8);
  return r.s;
}
static __device__ __forceinline__ f32x4 ald_f4(const void* p) {
  union { u64 u[2]; f32x4 f; } r;
  r.u[0] = ald64((const char*)p); r.u[1] = ald64((const char*)p + 8);
  return r.f;
}

// wave-wide window wait: lane watches one flag; invalid lanes auto-pass.
static __device__ __forceinline__ void wwait(const unsigned* p, bool ok, unsigned tgt) {
  for (;;) {
    unsigned v = ok ? ald32(p) : tgt;
    if (__ballot(v >= tgt) == ~0ull) break;
    __builtin_amdgcn_s_sleep(1);
  }
}

__global__ __launch_bounds__(256, 1)
void resrnn_kernel(const float* __restrict__ inp, const float* __restrict__ W1,
                   const float* __restrict__ b1f, const float* __restrict__ W2,
                   const float* __restrict__ b2f, float* __restrict__ out,
                   unsigned char* __restrict__ ws)
{
  const int tid   = threadIdx.x;
  const int bid   = blockIdx.x;
  const int group = bid & 3;
  const int chunk = bid >> 2;
  const int mbase = group * 32;
  const int n0    = chunk * 32;
  const int wave  = tid >> 6;
  const int lane  = tid & 63;
  const int l15   = lane & 15;
  const int q8    = (lane >> 4) * 8;
  const int kb    = wave * 512;

  // per-group flag arrays: slot (c*4 + producer_wave), 16B stride, monotone gen.
  unsigned* sflags = (unsigned*)(ws + group * 8192);          // S ready (chunks 0..61)
  unsigned* hflags = (unsigned*)(ws + group * 8192 + 4096);   // h ready (chunks 0..63)
  float* SfR = (float*)(ws + 32768);
  short* SbR = (short*)(ws + 32768 + 2 * SFN * 4);
  short* hbR = (short*)(ws + 32768 + 2 * SFN * 4 + 2 * SBN * 2);

  __shared__ float red1[4][16][65];
  __shared__ float red2[4][16][65];

  // ---- one-time: weight B-fragments into registers ----
  short8 B1[16][2], B2[16][2];
#pragma unroll
  for (int ks = 0; ks < 16; ++ks) {
#pragma unroll
    for (int nt = 0; nt < 2; ++nt) {
      const float* p1 = W1 + (size_t)(n0 + nt * 16 + l15) * WID + (kb + ks * 32 + q8);
      B1[ks][nt] = pack8(*(const f32x4*)p1, *(const f32x4*)(p1 + 4));
      const float* p2 = W2 + (size_t)(n0 + nt * 16 + l15) * WID + (kb + ks * 32 + q8);
      B2[ks][nt] = pack8(*(const f32x4*)p2, *(const f32x4*)(p2 + 4));
    }
  }

  const int m0 = mbase + l15;
  const int m1 = mbase + 16 + l15;
  const int o    = tid * 4;
  const int ml   = o >> 5;           // wave w's threads cover rows 8w..8w+7
  const int nl   = o & 31;
  const int mrow = mbase + ml;
  const f32x4 b1r = *(const f32x4*)(b1f + n0 + nl);
  const f32x4 b2r = *(const f32x4*)(b2f + n0 + nl);

  // poll pointers: lane = window_chunk(lane>>2) * 4 + producer_wave(lane&3)
  const int wv  = lane & 3;
  const int wc  = lane >> 2;
  const int p1c = 16 * wave + wc - 2;            // S window: chunks 16w-2 .. 16w+13
  const bool p1ok = (p1c >= 0);
  const unsigned* p1p = sflags + ((p1ok ? p1c : 0) * 4 + wv) * 4;
  const unsigned* p2p = hflags + ((16 * wave + wc) * 4 + wv) * 4;  // h window: 16w..16w+15

#pragma unroll 1
  for (int t = 0; t < NSTEPS; ++t) {
    const int sW = t & 1;
    const int sR = sW ^ 1;                       // (t-1)&1 for t>=1
    float*       SfNew = SfR + (size_t)sW * SFN;
    const float* SfOld = SfR + (size_t)sR * SFN;
    const short* SbOld = SbR + (size_t)sR * SBN;
    short*       SbNew = SbR + (size_t)sW * SBN;
    short*       hb    = hbR + (size_t)sW * HN;

    // ============ phase 1: u = s@W1^T ; h = |u+b1| ============
    if (t > 0) wwait(p1p, p1ok, (unsigned)t);    // ONE poll for all 16 producers
    f32x4 a00{}, a01{}, a10{}, a11{};
#pragma unroll
    for (int ks = 0; ks < 16; ++ks) {            // loads stream ungated
      if (kb == 0 && ks < 2) {
        const float* p0 = inp + ((size_t)t * NB + m0) * 64 + (ks * 32 + q8);
        const float* p1 = inp + ((size_t)t * NB + m1) * 64 + (ks * 32 + q8);
        short8 x0 = pack8(*(const f32x4*)p0, *(const f32x4*)(p0 + 4));
        short8 x1 = pack8(*(const f32x4*)p1, *(const f32x4*)(p1 + 4));
        a00 = __builtin_amdgcn_mfma_f32_16x16x32_bf16(x0, B1[ks][0], a00, 0, 0, 0);
        a01 = __builtin_amdgcn_mfma_f32_16x16x32_bf16(x0, B1[ks][1], a01, 0, 0, 0);
        a10 = __builtin_amdgcn_mfma_f32_16x16x32_bf16(x1, B1[ks][0], a10, 0, 0, 0);
        a11 = __builtin_amdgcn_mfma_f32_16x16x32_bf16(x1, B1[ks][1], a11, 0, 0, 0);
      } else if (t > 0) {
        short8 x0 = ald_s8(SbOld + (size_t)m0 * SS + (kb + ks * 32 - 64 + q8));
        short8 x1 = ald_s8(SbOld + (size_t)m1 * SS + (kb + ks * 32 - 64 + q8));
        a00 = __builtin_amdgcn_mfma_f32_16x16x32_bf16(x0, B1[ks][0], a00, 0, 0, 0);
        a01 = __builtin_amdgcn_mfma_f32_16x16x32_bf16(x0, B1[ks][1], a01, 0, 0, 0);
        a10 = __builtin_amdgcn_mfma_f32_16x16x32_bf16(x1, B1[ks][0], a10, 0, 0, 0);
        a11 = __builtin_amdgcn_mfma_f32_16x16x32_bf16(x1, B1[ks][1], a11, 0, 0, 0);
      }
    }
#pragma unroll
    for (int r = 0; r < 4; ++r) {
      red1[wave][r][lane]      = a00[r];
      red1[wave][4 + r][lane]  = a01[r];
      red1[wave][8 + r][lane]  = a10[r];
      red1[wave][12 + r][lane] = a11[r];
    }
    __syncthreads();   // gates epilogue behind the WG-wide union of S-waits
    {
      short4v hv;
#pragma unroll
      for (int j = 0; j < 4; ++j) {
        const int nn   = nl + j;
        const int lidx = ((ml >> 2) & 3) * 16 + (nn & 15);
        const int ridx = (ml >> 4) * 8 + (nn >> 4) * 4 + (ml & 3);
        float s = red1[0][ridx][lidx] + red1[1][ridx][lidx]
                + red1[2][ridx][lidx] + red1[3][ridx][lidx] + b1r[j];
        hv[j] = f2bf(fabsf(s));
      }
      union { short4v s; u64 u; } hu; hu.s = hv;
      ast64(hb + (size_t)mrow * WID + (n0 + nl), hu.u);
    }
    asm volatile("s_waitcnt vmcnt(0)" ::: "memory");   // this wave's h at LLC
    if (lane == 0)
      ast32(hflags + (chunk * 4 + wave) * 4, (unsigned)t + 1);

    // ============ phase 2: g = h@W2^T ; state update ============
    wwait(p2p, true, (unsigned)t + 1);           // ONE poll for all 16 producers
    f32x4 c00{}, c01{}, c10{}, c11{};
    {
      const short* h0 = hb + (size_t)m0 * WID + kb + q8;
      const short* h1 = hb + (size_t)m1 * WID + kb + q8;
#pragma unroll
      for (int ks = 0; ks < 16; ++ks) {          // loads stream ungated
        short8 x0 = ald_s8(h0 + ks * 32);
        short8 x1 = ald_s8(h1 + ks * 32);
        c00 = __builtin_amdgcn_mfma_f32_16x16x32_bf16(x0, B2[ks][0], c00, 0, 0, 0);
        c01 = __builtin_amdgcn_mfma_f32_16x16x32_bf16(x0, B2[ks][1], c01, 0, 0, 0);
        c10 = __builtin_amdgcn_mfma_f32_16x16x32_bf16(x1, B2[ks][0], c10, 0, 0, 0);
        c11 = __builtin_amdgcn_mfma_f32_16x16x32_bf16(x1, B2[ks][1], c11, 0, 0, 0);
      }
    }
#pragma unroll
    for (int r = 0; r < 4; ++r) {
      red2[wave][r][lane]      = c00[r];
      red2[wave][4 + r][lane]  = c01[r];
      red2[wave][8 + r][lane]  = c10[r];
      red2[wave][12 + r][lane] = c11[r];
    }
    __syncthreads();   // gates epilogue behind the WG-wide union of h-waits
    if (t < NSTEPS - 1) {
      if (n0 < SS) {
        f32x4 gv;
#pragma unroll
        for (int j = 0; j < 4; ++j) {
          const int nn   = nl + j;
          const int lidx = ((ml >> 2) & 3) * 16 + (nn & 15);
          const int ridx = (ml >> 4) * 8 + (nn >> 4) * 4 + (ml & 3);
          gv[j] = red2[0][ridx][lidx] + red2[1][ridx][lidx]
                + red2[2][ridx][lidx] + red2[3][ridx][lidx] + b2r[j];
        }
        const int c0 = n0 + nl;
        f32x4 prev;
        if (c0 < 64) {
          prev = *(const f32x4*)(inp + ((size_t)t * NB + mrow) * 64 + c0);
        } else if (t > 0) {   // chunk-2 covered by the WG-wide union of phase-1 waits
          prev = ald_f4(SfOld + (size_t)mrow * SS + (c0 - 64));
        } else {
          prev = f32x4{0.f, 0.f, 0.f, 0.f};
        }
        f32x4 sv; short4v sb;
#pragma unroll
        for (int j = 0; j < 4; ++j) {
          float vv = 0.9f * prev[j] + 0.1f * gv[j];
          sv[j] = vv; sb[j] = f2bf(vv);
        }
        union { f32x4 f; u64 u[2]; } sfu; sfu.f = sv;
        float* pf = SfNew + (size_t)mrow * SS + c0;
        ast64(pf, sfu.u[0]);
        ast64(pf + 2, sfu.u[1]);
        union { short4v s; u64 u; } sbu; sbu.s = sb;
        ast64(SbNew + (size_t)mrow * SS + c0, sbu.u);
      }
      asm volatile("s_waitcnt vmcnt(0)" ::: "memory");
      if (lane == 0 && chunk < 62)
        ast32(sflags + (chunk * 4 + wave) * 4, (unsigned)t + 1);
    } else {
      if (n0 >= SS) {
        f32x4 gv;
#pragma unroll
        for (int j = 0; j < 4; ++j) {
          const int nn   = nl + j;
          const int lidx = ((ml >> 2) & 3) * 16 + (nn & 15);
          const int ridx = (ml >> 4) * 8 + (nn >> 4) * 4 + (ml & 3);
          gv[j] = red2[0][ridx][lidx] + red2[1][ridx][lidx]
                + red2[2][ridx][lidx] + red2[3][ridx][lidx] + b2r[j];
        }
        const int c0 = n0 + nl;
        f32x4 prev = ald_f4(SfOld + (size_t)mrow * SS + (c0 - 64));
        f32x4 ov;
#pragma unroll
        for (int j = 0; j < 4; ++j) ov[j] = 0.9f * prev[j] + 0.1f * gv[j];
        *(f32x4*)(out + (size_t)mrow * 64 + (c0 - SS)) = ov;
      }
    }
  }
}

extern "C" void kernel_launch(void* const* d_in, const int* in_sizes, int n_in,
                              void* d_out, int out_size, void* d_ws, size_t ws_size,
                              hipStream_t stream)
{
  (void)in_sizes; (void)n_in; (void)out_size; (void)ws_size;
  const float* inp = (const float*)d_in[0];
  const float* W1  = (const float*)d_in[1];
  const float* b1  = (const float*)d_in[2];
  const float* W2  = (const float*)d_in[3];
  const float* b2  = (const float*)d_in[4];
  float* out = (float*)d_out;

  hipMemsetAsync(d_ws, 0, 32768, stream);  // flag arrays
  resrnn_kernel<<<dim3(256), dim3(256), 0, stream>>>(
      inp, W1, b1, W2, b2, out, (unsigned char*)d_ws);
}